// Round 9
// baseline (27206.802 us; speedup 1.0000x reference)
//
#include <hip/hip_runtime.h>
#include <stdint.h>

#define TSTEPS 8192
#define HDIM 512
#define LDS_BYTES 135168   // 64*512 W_ih + 512 hA + 512 hB, f32
#define WARM 32            // steps using Q path before trying fast path
#define FASTK 4096         // fast-poll rounds before sticky fallback

typedef unsigned long long ull;
typedef unsigned int uint4v __attribute__((ext_vector_type(4)));

// ---------------------------------------------------------------------------
__device__ __forceinline__ ull pack_th(unsigned tag, float v) {
    union { float f; unsigned u; } x; x.f = v;
    return ((ull)tag << 32) | (ull)x.u;
}
__device__ __forceinline__ float unpack_v(ull p) {
    union { unsigned u; float f; } x; x.u = (unsigned)p;
    return x.f;
}
__device__ __forceinline__ float bits_f(unsigned u) {
    union { unsigned u; float f; } x; x.u = u;
    return x.f;
}
// 16B load that bypasses L1 and reads the XCD-shared L2 (fast path).
__device__ __forceinline__ uint4v sc0_load16(const ull* p) {
    uint4v r;
    asm volatile("global_load_dwordx4 %0, %1, off sc0\n\ts_waitcnt vmcnt(0)"
                 : "=v"(r) : "v"(p) : "memory");
    return r;
}

// ---------------------------------------------------------------------------
// Fused 2-layer persistent LSTM with XCD-local fast sync.
// Grid 256: role = bid&7. role0 = layer1 (intended XCD0, 32 WGs), role1 =
// layer2 (XCD1); roles 2..7 exit. WG wg=bid>>3 owns units [wg*16,wg*16+16).
// Lane = u_in_wave*16 + q: unit u_local = wave*4+u_in_wave, k-chunk q*32.
// W_hh: 128 f32/thread in VGPRs, PRE-ROTATED (static reg indices; runtime
//   rotation only in LDS addresses — avoids scratch, rule #20).
// W_ih: [64][512] f32 in LDS (feed dot is off the critical path).
// Publish = DUAL STORE: plain 8B -> P-ring (dirty line in producer's XCD L2;
//   visible to same-XCD sc0 loads in ~90ns) + agent atomic -> Q-ring (LLC,
//   always globally visible). Consumers: warm-up on Q; then sc0 fast-poll on
//   P with sticky fallback to Q after FASTK misses. Correct under ANY
//   placement (G16): fallback path never depends on XCD locality; P-line
//   eviction writes back to LLC, refetch sees fresh data.
// Rings FULL-HISTORY (slot s = state after s steps, tag s+1; d_ws re-poisoned
//   0xAA each launch -> tags never false-match).
// L2's feed (h1 from XCD0) is ALWAYS read via Q (cross-XCD), off-path.
// ---------------------------------------------------------------------------
__global__ __attribute__((amdgpu_waves_per_eu(1, 1))) __launch_bounds__(256)
void lstm_fused(
    const float* __restrict__ x,      // [T][512]
    const float* __restrict__ Whh0, const float* __restrict__ Wih0,
    const float* __restrict__ bih0, const float* __restrict__ bhh0,
    const float* __restrict__ Wih1, const float* __restrict__ Whh1,
    const float* __restrict__ bih1, const float* __restrict__ bhh1,
    const float* __restrict__ h0,     // [2][512]
    const float* __restrict__ c0,     // [2][512]
    float* __restrict__ h2seq,        // [T][512]
    ull* __restrict__ r0P, ull* __restrict__ r0Q,   // h1 rings [T+2][512]
    ull* __restrict__ r1P, ull* __restrict__ r1Q)   // h2 rings [T+2][512]
{
    const int role = (int)blockIdx.x & 7;
    if (role >= 2) return;                 // 192 dummy blocks exit
    const int L2 = role;
    const int wg = (int)blockIdx.x >> 3;   // 0..31

    extern __shared__ float lds[];
    float* sWB = lds;            // [64][512] feed weights (row = u_local*4+r)
    float* hA  = lds + 32768;    // [512] recurrent h (single buf, 2 barriers)
    float* hB  = lds + 33280;    // [512] feed vector

    const int tid  = threadIdx.x;
    const int wave = tid >> 6;
    const int lane = tid & 63;
    const int uw   = lane >> 4;           // unit within wave 0..3
    const int q    = lane & 15;           // k-chunk: cols [q*32, q*32+32)
    const int ul   = wave * 4 + uw;       // unit within WG 0..15
    const int j    = wg * 16 + ul;        // global hidden unit

    ull* rPs = L2 ? r1P : r0P;            // self rings
    ull* rQs = L2 ? r1Q : r0Q;

    // ---- initial state publish first (max propagation slack) --------------
    if (q == 0) {
        const float h00 = h0[(L2 ? HDIM : 0) + j];
        *(volatile ull*)&rPs[j] = pack_th(1u, h00);
        __hip_atomic_store(&rQs[j], pack_th(1u, h00),
                           __ATOMIC_RELAXED, __HIP_MEMORY_SCOPE_AGENT);
    }

    // ---- W_hh into VGPRs, pre-rotated by q ---------------------------------
    float4 wA[4][8];
    {
        const float* WA = L2 ? Whh1 : Whh0;
#pragma unroll
        for (int r = 0; r < 4; ++r) {
            const float* row = WA + (size_t)(r * HDIM + j) * HDIM + q * 32;
#pragma unroll
            for (int i = 0; i < 8; ++i)
                wA[r][i] = *(const float4*)&row[4 * ((i + q) & 7)];
        }
    }
    // ---- W_ih into LDS -----------------------------------------------------
    {
        const float* WB = L2 ? Wih1 : Wih0;
        const int rr = tid >> 2, qq = tid & 3;        // row 0..63, quarter
        const int u_r = rr >> 2, g_r = rr & 3;
        const float4* src = (const float4*)&WB[(size_t)(g_r * HDIM + wg * 16 + u_r) * HDIM + qq * 128];
        float4* dst = (float4*)&sWB[rr * 512 + qq * 128];
#pragma unroll
        for (int i = 0; i < 32; ++i) dst[i] = src[i];
    }
    float bb[4];
#pragma unroll
    for (int r = 0; r < 4; ++r)
        bb[r] = L2 ? (bih1[r * HDIM + j] + bhh1[r * HDIM + j])
                   : (bih0[r * HDIM + j] + bhh0[r * HDIM + j]);
    float c = c0[(L2 ? HDIM : 0) + j];

    // ---- feed(0) -> hB -----------------------------------------------------
    if (!L2) {
        float2 v = *(const float2*)&x[2 * tid];
        hB[2 * tid] = v.x; hB[2 * tid + 1] = v.y;
    } else {
        const ull* s = r0Q + (size_t)1 * HDIM;        // h1(0): slot 1, tag 2
        ull p0, p1;
        do {
            p0 = __hip_atomic_load(&s[2 * tid],     __ATOMIC_RELAXED, __HIP_MEMORY_SCOPE_AGENT);
            p1 = __hip_atomic_load(&s[2 * tid + 1], __ATOMIC_RELAXED, __HIP_MEMORY_SCOPE_AGENT);
            if ((unsigned)(p0 >> 32) == 2u && (unsigned)(p1 >> 32) == 2u) break;
            __builtin_amdgcn_s_sleep(1);
        } while (1);
        hB[2 * tid] = unpack_v(p0); hB[2 * tid + 1] = unpack_v(p1);
    }
    __syncthreads();

    bool fast = true;
    for (int t = 0; t < TSTEPS; ++t) {
        // ---- A: feed dot from hB + W_ih(LDS); overlaps publish propagation
        float pre0 = 0.f, pre1 = 0.f, pre2 = 0.f, pre3 = 0.f;
        {
            const float* hb = &hB[q * 32];
            float4 hr[8];
#pragma unroll
            for (int i = 0; i < 8; ++i) hr[i] = *(const float4*)&hb[4 * ((i + q) & 7)];
#pragma unroll
            for (int r = 0; r < 4; ++r) {
                const float* wr = &sWB[(ul * 4 + r) * 512 + q * 32];
                float a = 0.f;
#pragma unroll
                for (int i = 0; i < 8; ++i) {
                    const float4 wq = *(const float4*)&wr[4 * ((i + q) & 7)];
                    a += wq.x * hr[i].x + wq.y * hr[i].y + wq.z * hr[i].z + wq.w * hr[i].w;
                }
                if (r == 0) pre0 = a; else if (r == 1) pre1 = a;
                else if (r == 2) pre2 = a; else pre3 = a;
            }
        }
        float2 xn;
        if (!L2 && t + 1 < TSTEPS)
            xn = *(const float2*)&x[(size_t)(t + 1) * HDIM + 2 * tid];

        // ---- B: poll self-ring row t (tag t+1) -> hA ----------------------
        {
            const unsigned tg = (unsigned)(t + 1);
            float v0, v1; bool have = false;
            if (fast && t >= WARM) {
                int tries = 0; uint4v v;
                do {
                    v = sc0_load16(&rPs[(size_t)t * HDIM + 2 * tid]);
                    if (v.y == tg && v.w == tg) { have = true; break; }
                } while (++tries < FASTK);
                if (have) { v0 = bits_f(v.x); v1 = bits_f(v.z); }
                else fast = false;                    // sticky fallback
            }
            if (!have) {
                const ull* s = rQs + (size_t)t * HDIM;
                ull p0, p1;
                do {
                    p0 = __hip_atomic_load(&s[2 * tid],     __ATOMIC_RELAXED, __HIP_MEMORY_SCOPE_AGENT);
                    p1 = __hip_atomic_load(&s[2 * tid + 1], __ATOMIC_RELAXED, __HIP_MEMORY_SCOPE_AGENT);
                    if ((unsigned)(p0 >> 32) == tg && (unsigned)(p1 >> 32) == tg) break;
                    __builtin_amdgcn_s_sleep(1);
                } while (1);
                v0 = unpack_v(p0); v1 = unpack_v(p1);
            }
            hA[2 * tid] = v0; hA[2 * tid + 1] = v1;
        }
        __syncthreads();   // MID barrier

        // ---- C: recurrent dot (W_hh VGPR x hA LDS), reduce over 16 lanes --
        float a0, a1, a2, a3;
        {
            const float* ha = &hA[q * 32];
            float4 hr[8];
#pragma unroll
            for (int i = 0; i < 8; ++i) hr[i] = *(const float4*)&ha[4 * ((i + q) & 7)];
            a0 = pre0; a1 = pre1; a2 = pre2; a3 = pre3;
#pragma unroll
            for (int i = 0; i < 8; ++i) {
                a0 += wA[0][i].x * hr[i].x + wA[0][i].y * hr[i].y + wA[0][i].z * hr[i].z + wA[0][i].w * hr[i].w;
                a1 += wA[1][i].x * hr[i].x + wA[1][i].y * hr[i].y + wA[1][i].z * hr[i].z + wA[1][i].w * hr[i].w;
                a2 += wA[2][i].x * hr[i].x + wA[2][i].y * hr[i].y + wA[2][i].z * hr[i].z + wA[2][i].w * hr[i].w;
                a3 += wA[3][i].x * hr[i].x + wA[3][i].y * hr[i].y + wA[3][i].z * hr[i].z + wA[3][i].w * hr[i].w;
            }
        }
#pragma unroll
        for (int m = 1; m < 16; m <<= 1) {
            a0 += __shfl_xor(a0, m);
            a1 += __shfl_xor(a1, m);
            a2 += __shfl_xor(a2, m);
            a3 += __shfl_xor(a3, m);
        }
        const float iv = 1.f / (1.f + __expf(-(a0 + bb[0])));
        const float ff = 1.f / (1.f + __expf(-(a1 + bb[1])));
        const float gg = 1.f - 2.f / (__expf(2.f * (a2 + bb[2])) + 1.f);
        const float ov = 1.f / (1.f + __expf(-(a3 + bb[3])));
        c = ff * c + iv * gg;
        const float h = ov * (1.f - 2.f / (__expf(2.f * c) + 1.f));

        // ---- D: dual publish ---------------------------------------------
        if (q == 0) {
            const ull pk = pack_th((unsigned)(t + 2), h);
            *(volatile ull*)&rPs[(size_t)(t + 1) * HDIM + j] = pk;
            __hip_atomic_store(&rQs[(size_t)(t + 1) * HDIM + j], pk,
                               __ATOMIC_RELAXED, __HIP_MEMORY_SCOPE_AGENT);
        }
        if (L2 && q == 1) h2seq[(size_t)t * HDIM + j] = h;

        // ---- E: stage feed(t+1) -> hB ------------------------------------
        if (t + 1 < TSTEPS) {
            if (!L2) {
                hB[2 * tid] = xn.x; hB[2 * tid + 1] = xn.y;
            } else {
                const ull* s = r0Q + (size_t)(t + 2) * HDIM;   // h1(t+1)
                const unsigned tg = (unsigned)(t + 3);
                ull p0, p1;
                do {
                    p0 = __hip_atomic_load(&s[2 * tid],     __ATOMIC_RELAXED, __HIP_MEMORY_SCOPE_AGENT);
                    p1 = __hip_atomic_load(&s[2 * tid + 1], __ATOMIC_RELAXED, __HIP_MEMORY_SCOPE_AGENT);
                    if ((unsigned)(p0 >> 32) == tg && (unsigned)(p1 >> 32) == tg) break;
                    __builtin_amdgcn_s_sleep(1);
                } while (1);
                hB[2 * tid] = unpack_v(p0); hB[2 * tid + 1] = unpack_v(p1);
            }
        }
        __syncthreads();   // END barrier (protects hA/hB reuse)
    }
}

// ---------------------------------------------------------------------------
// Head + BCE loss.
// ---------------------------------------------------------------------------
__global__ __launch_bounds__(256) void head_loss(
    const float* __restrict__ h2,   // [T][512]
    const float* __restrict__ Wh,   // [2][512]
    const float* __restrict__ bh,   // [2]
    const float* __restrict__ y,    // [T][2]
    float* __restrict__ out)
{
    const int tid  = threadIdx.x;
    const int lane = tid & 63;
    const int wv   = tid >> 6;
    const int gw   = blockIdx.x * 4 + wv;   // 0..1023

    float w0[8], w1[8];
#pragma unroll
    for (int u = 0; u < 8; ++u) {
        w0[u] = Wh[lane * 8 + u];
        w1[u] = Wh[HDIM + lane * 8 + u];
    }

    float lsum = 0.f;
    for (int t = gw; t < TSTEPS; t += 1024) {
        const float* hp = h2 + (size_t)t * HDIM + lane * 8;
        float4 hv0 = *(const float4*)&hp[0];
        float4 hv1 = *(const float4*)&hp[4];
        float a0 = hv0.x * w0[0] + hv0.y * w0[1] + hv0.z * w0[2] + hv0.w * w0[3]
                 + hv1.x * w0[4] + hv1.y * w0[5] + hv1.z * w0[6] + hv1.w * w0[7];
        float a1 = hv0.x * w1[0] + hv0.y * w1[1] + hv0.z * w1[2] + hv0.w * w1[3]
                 + hv1.x * w1[4] + hv1.y * w1[5] + hv1.z * w1[6] + hv1.w * w1[7];
#pragma unroll
        for (int m = 1; m < 64; m <<= 1) {
            a0 += __shfl_xor(a0, m);
            a1 += __shfl_xor(a1, m);
        }
        if (lane == 0) {
            const float z0 = a0 + bh[0];
            const float z1 = a1 + bh[1];
            const float p0 = 1.f / (1.f + __expf(-z0));
            const float p1 = 1.f / (1.f + __expf(-z1));
            const float lp0  = fmaxf(__logf(p0), -100.f);
            const float lp1  = fmaxf(__logf(p1), -100.f);
            const float l1p0 = fmaxf(log1pf(-p0), -100.f);
            const float l1p1 = fmaxf(log1pf(-p1), -100.f);
            const float y0 = y[(size_t)t * 2 + 0];
            const float y1 = y[(size_t)t * 2 + 1];
            lsum += y0 * lp0 + (1.f - y0) * l1p0;
            lsum += y1 * lp1 + (1.f - y1) * l1p1;
        }
    }

    __shared__ float red[4];
    if (lane == 0) red[wv] = lsum;
    __syncthreads();
    if (tid == 0) {
        const float ssum = red[0] + red[1] + red[2] + red[3];
        atomicAdd(out, ssum * (-1.f / (float)(TSTEPS * 2)));
    }
}

// ---------------------------------------------------------------------------
extern "C" void kernel_launch(void* const* d_in, const int* in_sizes, int n_in,
                              void* d_out, int out_size, void* d_ws, size_t ws_size,
                              hipStream_t stream)
{
    const float* x     = (const float*)d_in[0];   // [8192][1][512]
    const float* truth = (const float*)d_in[1];   // [8192][1][2]
    const float* h0    = (const float*)d_in[2];   // [2][1][512]
    const float* c0    = (const float*)d_in[3];   // [2][1][512]
    const float* Wih0  = (const float*)d_in[4];
    const float* Whh0  = (const float*)d_in[5];
    const float* bih0  = (const float*)d_in[6];
    const float* bhh0  = (const float*)d_in[7];
    const float* Wih1  = (const float*)d_in[8];
    const float* Whh1  = (const float*)d_in[9];
    const float* bih1  = (const float*)d_in[10];
    const float* bhh1  = (const float*)d_in[11];
    const float* Whead = (const float*)d_in[12];
    const float* bhead = (const float*)d_in[13];

    char* ws = (char*)d_ws;
    ull*   r0P   = (ull*)ws;                               // 33.6 MB [8194][512]
    ull*   r0Q   = (ull*)(ws + (((size_t)34)  << 20));
    ull*   r1P   = (ull*)(ws + (((size_t)68)  << 20));
    ull*   r1Q   = (ull*)(ws + (((size_t)102) << 20));
    float* h2seq = (float*)(ws + (((size_t)136) << 20));   // 16 MB [T][512]

    hipMemsetAsync(d_out, 0, (size_t)out_size * sizeof(float), stream);

    hipFuncSetAttribute((const void*)lstm_fused,
                        hipFuncAttributeMaxDynamicSharedMemorySize, LDS_BYTES);

    lstm_fused<<<256, 256, LDS_BYTES, stream>>>(x, Whh0, Wih0, bih0, bhh0,
                                                Wih1, Whh1, bih1, bhh1,
                                                h0, c0, h2seq,
                                                r0P, r0Q, r1P, r1Q);
    head_loss<<<256, 256, 0, stream>>>(h2seq, Whead, bhead, truth, (float*)d_out);
}